// Round 1
// 1228.924 us; speedup vs baseline: 1.0576x; 1.0576x over previous
//
#include <hip/hip_runtime.h>
#include <stdint.h>

// Problem constants (B, D, L, K from the reference). fp32 I/O per reference.
#define NB 4096
#define DD 2048
#define LL 16384
#define KT 64
#define WCAP 24        // window candidate cap per row
#define TAU 1.2e-2f    // sure/window margin: 5.7 sigma of zhat error (hh-only)
#define T3 1e-4f       // tier-3 exact-fp64 gap threshold (matches round-3 exposure)

typedef unsigned short u16;
typedef __bf16 bf16x8 __attribute__((ext_vector_type(8)));
typedef float f32x4 __attribute__((ext_vector_type(4)));
typedef unsigned short u16x4 __attribute__((ext_vector_type(4)));
typedef unsigned short u16x8 __attribute__((ext_vector_type(8)));

__device__ __forceinline__ float bf2f(u16 b) {
  return __uint_as_float(((unsigned)b) << 16);
}
__device__ __forceinline__ u16 f2bf(float f) {
  unsigned u = __float_as_uint(f);
  unsigned r = u + 0x7fffu + ((u >> 16) & 1u);  // RNE
  return (u16)(r >> 16);
}

// ---------------------------------------------------------------------------
// Kernel 1: X fp32 -> Xh bf16 (hi part only; fixup reads fp32 X directly)
// ---------------------------------------------------------------------------
__global__ __launch_bounds__(256) void prep_x(const float* __restrict__ X,
                                              u16* __restrict__ Xh) {
  int i = (blockIdx.x * 256 + threadIdx.x) * 4;
  float4 v = *(const float4*)(X + i);
  u16x4 h;
  h[0] = f2bf(v.x); h[1] = f2bf(v.y); h[2] = f2bf(v.z); h[3] = f2bf(v.w);
  *(u16x4*)(Xh + i) = h;
}

// ---------------------------------------------------------------------------
// Kernel 2: transpose + split W fp32 [2048,16384] -> Wh/Wl bf16 [16384,2048]
// ---------------------------------------------------------------------------
__global__ __launch_bounds__(256) void prep_w(const float* __restrict__ W,
                                              u16* __restrict__ Wh,
                                              u16* __restrict__ Wl) {
  __shared__ float tile[64][65];  // +1 pad breaks write-phase bank aliasing
  int l0 = blockIdx.x * 64, d0 = blockIdx.y * 64;
  int t = threadIdx.x;
  int lx = (t & 15) * 4;
  int dq = t >> 4;
#pragma unroll
  for (int p = 0; p < 4; ++p) {
    int d = dq + p * 16;
    float4 v = *(const float4*)(W + (size_t)(d0 + d) * LL + l0 + lx);
    tile[d][lx + 0] = v.x; tile[d][lx + 1] = v.y;
    tile[d][lx + 2] = v.z; tile[d][lx + 3] = v.w;
  }
  __syncthreads();
  int dx = (t & 15) * 4;
  int lq = t >> 4;
#pragma unroll
  for (int p = 0; p < 4; ++p) {
    int l = lq + p * 16;
    u16x4 h, lo;
#pragma unroll
    for (int q = 0; q < 4; ++q) {
      float w = tile[dx + q][l];
      u16 hb = f2bf(w);
      h[q] = hb;
      lo[q] = f2bf(w - bf2f(hb));
    }
    size_t o = (size_t)(l0 + l) * DD + d0 + dx;
    *(u16x4*)(Wh + o) = h;
    *(u16x4*)(Wl + o) = lo;
  }
}

// ---------------------------------------------------------------------------
// Kernel 3: encode GEMM  zhat = Xh·Wh^T + benc
// 256x256 tile, BK=64, 8 waves (2Mx4N, 128x64 out/wave), 8-phase schedule
// (guide §5 m201 template): per phase {ds_read subtile || stage half-tile ->
// s_barrier -> lgkmcnt(0) -> setprio(1) -> 16 MFMA -> setprio(0) -> barrier},
// counted vmcnt(6) only at phases 4/8, XOR bank-swizzle (granule ^= row&7)
// applied on BOTH the pre-swizzled global_load_lds source and the ds_read
// address (rule #21). Staging of a buffer region is issued strictly after the
// phase whose barrier retired the last read of its previous contents.
// Numerics identical to the 128² version (same MFMA, same K order) so the
// TAU window / fixup analysis is unchanged.
// ---------------------------------------------------------------------------
#define TBM 256
#define TBN 256
#define TBK 64
#define NKT (DD / TBK)  // 32 K-tiles, 16 iterations of 2

__device__ __forceinline__ void async16(const u16* g, u16* l) {
  __builtin_amdgcn_global_load_lds(
      (const __attribute__((address_space(1))) unsigned int*)g,
      (__attribute__((address_space(3))) unsigned int*)l, 16, 0, 0);
}

// HF: 0=A.h0 1=A.h1 2=B.h0 3=B.h1 (compile-time); TAU_ = K-tile index.
// Each thread issues 2 global_load_lds (q=0: rows 0-63 of the half, q=1:
// rows 64-127). LDS dest is linear (wave-uniform base + lane*16); the
// global source column granule is pre-swizzled with (s ^ (row&7)).
#define STAGE(HF, TAU_)                                                      \
  do {                                                                       \
    const u16* g_ = ((HF) < 2 ? Abase : Bbase) +                             \
                    (size_t)(((HF)&1) * 128 + rr) * DD + ((TAU_) << 6) +     \
                    scol;                                                    \
    u16* l_ = ((HF) < 2 ? As : Bs) + ((TAU_)&1) * (TBM * TBK) +              \
              (((HF)&1) * 128) * TBK + t * 8;                                \
    async16(g_, l_);                                                         \
    async16(g_ + (size_t)64 * DD, l_ + 4096);                                \
  } while (0)

// Load one A m-quadrant (4 mreps x 2 ksubs = 8 x ds_read_b128) into DST.
#define LDA(DST, DB, MQ)                                                     \
  do {                                                                       \
    const u16* p_ = As + (DB) * (TBM * TBK) + (wm + (MQ)*64 + fr) * TBK;     \
    _Pragma("unroll") for (int i_ = 0; i_ < 4; ++i_) {                       \
      DST[i_][0] = *(const bf16x8*)(p_ + i_ * (16 * TBK) + c0);              \
      DST[i_][1] = *(const bf16x8*)(p_ + i_ * (16 * TBK) + c1);              \
    }                                                                        \
  } while (0)

// Load one B n-quadrant (2 nreps x 2 ksubs = 4 x ds_read_b128) into bq.
#define LDBQ(DB, NQ)                                                         \
  do {                                                                       \
    const u16* p_ = Bs + (DB) * (TBN * TBK) + (wn + (NQ)*32 + fr) * TBK;     \
    _Pragma("unroll") for (int j_ = 0; j_ < 2; ++j_) {                       \
      bq[j_][0] = *(const bf16x8*)(p_ + j_ * (16 * TBK) + c0);               \
      bq[j_][1] = *(const bf16x8*)(p_ + j_ * (16 * TBK) + c1);               \
    }                                                                        \
  } while (0)

// One C-quadrant x K=64: 4x2 frags x 2 chained ksubs = 16 MFMA.
#define MFMAQ(AF, MQ, NQ)                                                    \
  do {                                                                       \
    _Pragma("unroll") for (int i_ = 0; i_ < 4; ++i_)                         \
        _Pragma("unroll") for (int j_ = 0; j_ < 2; ++j_) {                   \
      f32x4 a_ = acc[(MQ)*4 + i_][(NQ)*2 + j_];                              \
      a_ = __builtin_amdgcn_mfma_f32_16x16x32_bf16(AF[i_][0], bq[j_][0], a_, \
                                                   0, 0, 0);                 \
      a_ = __builtin_amdgcn_mfma_f32_16x16x32_bf16(AF[i_][1], bq[j_][1], a_, \
                                                   0, 0, 0);                 \
      acc[(MQ)*4 + i_][(NQ)*2 + j_] = a_;                                    \
    }                                                                        \
  } while (0)

#define BAR __builtin_amdgcn_s_barrier()
#define LGKM0 asm volatile("s_waitcnt lgkmcnt(0)")
#define PRIO1 __builtin_amdgcn_s_setprio(1)
#define PRIO0 __builtin_amdgcn_s_setprio(0)

__global__ __launch_bounds__(512, 2) void encode_gemm(
    const u16* __restrict__ Xh,   // [rows,2048] (pre-offset to chunk)
    const u16* __restrict__ Wh,   // [16384,2048]
    const float* __restrict__ benc,
    float* __restrict__ Z) {      // [rows,16384]
  __shared__ u16 As[2 * TBM * TBK];  // 64 KB (2 dbuf x 256 x 64)
  __shared__ u16 Bs[2 * TBN * TBK];  // 64 KB
  int t = threadIdx.x;
  int m0 = blockIdx.y * TBM;
  int n0 = blockIdx.x * TBN;

  int lane = t & 63, w = t >> 6;
  int wm = (w & 1) * 128;   // wave M offset (2 waves in M)
  int wn = (w >> 1) * 64;   // wave N offset (4 waves in N)
  int fr = lane & 15;
  int fq = lane >> 4;
  // swizzled ds_read column granules (elements), ksub 0 / ksub 1
  int c0 = ((fq ^ (fr & 7)) << 3);
  int c1 = (((4 + fq) ^ (fr & 7)) << 3);
  // staging: thread t covers row rr (per q: +0/+64), slot t&7, swizzled src
  int rr = t >> 3;
  int scol = (((t & 7) ^ (rr & 7)) << 3);

  const u16* Abase = Xh + (size_t)m0 * DD;
  const u16* Bbase = Wh + (size_t)n0 * DD;

  f32x4 acc[8][4] = {};
  bf16x8 af0[4][2], af1[4][2], bq[2][2];

  // ---- prologue: stage tile0 (4 halves) + tile1 {Ah0,Ah1,Bh0} ----
  STAGE(0, 0); STAGE(1, 0); STAGE(2, 0); STAGE(3, 0);
  asm volatile("s_waitcnt vmcnt(4)" ::: "memory");
  STAGE(0, 1); STAGE(1, 1); STAGE(2, 1);
  asm volatile("s_waitcnt vmcnt(6)" ::: "memory");  // tile0 fully landed
  BAR;

  for (int it = 0; it < NKT / 2; ++it) {
    const int notlast = (it < NKT / 2 - 1);
    // ================= tile 2it (buf0) =================
    // P1: Q(0,0) — 12 ds_reads; stage [2it+1].Bh1 (buf1.B free since prev P7)
    LDA(af0, 0, 0);
    LDBQ(0, 0);
    STAGE(3, 2 * it + 1);
    asm volatile("s_waitcnt lgkmcnt(8)");
    BAR; LGKM0; PRIO1; MFMAQ(af0, 0, 0); PRIO0; BAR;
    // P2: Q(1,0) — 8 ds_reads (last reads of buf0.A)
    LDA(af1, 0, 1);
    BAR; LGKM0; PRIO1; MFMAQ(af1, 1, 0); PRIO0; BAR;
    // P3: Q(0,1) — 4 ds_reads (last reads of buf0.B); stage [2it+2].Ah0
    LDBQ(0, 1);
    if (notlast) STAGE(0, 2 * it + 2);
    BAR; LGKM0; PRIO1; MFMAQ(af0, 0, 1); PRIO0; BAR;
    // P4: Q(1,1) — no reads; stage [2it+2].{Ah1,Bh0}; counted vmcnt gate
    if (notlast) { STAGE(1, 2 * it + 2); STAGE(2, 2 * it + 2); }
    BAR; LGKM0; PRIO1; MFMAQ(af1, 1, 1); PRIO0;
    if (notlast) asm volatile("s_waitcnt vmcnt(6)" ::: "memory");
    else         asm volatile("s_waitcnt vmcnt(0)" ::: "memory");
    BAR;  // tile 2it+1 fully landed in buf1
    // ================= tile 2it+1 (buf1) =================
    // P5: Q(0,0); stage [2it+2].Bh1 (buf0.B free since P3)
    LDA(af0, 1, 0);
    LDBQ(1, 0);
    if (notlast) STAGE(3, 2 * it + 2);
    asm volatile("s_waitcnt lgkmcnt(8)");
    BAR; LGKM0; PRIO1; MFMAQ(af0, 0, 0); PRIO0; BAR;
    // P6: Q(1,0) — last reads of buf1.A
    LDA(af1, 1, 1);
    BAR; LGKM0; PRIO1; MFMAQ(af1, 1, 0); PRIO0; BAR;
    // P7: Q(0,1) — last reads of buf1.B; stage [2it+3].Ah0
    LDBQ(1, 1);
    if (notlast) STAGE(0, 2 * it + 3);
    BAR; LGKM0; PRIO1; MFMAQ(af0, 0, 1); PRIO0; BAR;
    // P8: Q(1,1); stage [2it+3].{Ah1,Bh0}; counted vmcnt gate
    if (notlast) { STAGE(1, 2 * it + 3); STAGE(2, 2 * it + 3); }
    BAR; LGKM0; PRIO1; MFMAQ(af1, 1, 1); PRIO0;
    if (notlast) asm volatile("s_waitcnt vmcnt(6)" ::: "memory");
    BAR;  // tile 2it+2 fully landed in buf0
  }

  // ---- epilogue: C/D layout col = lane&15, row = (lane>>4)*4 + reg ----
  int rbase = m0 + wm + fq * 4;
#pragma unroll
  for (int nr = 0; nr < 4; ++nr) {
    int col = n0 + wn + nr * 16 + fr;
    float be = benc[col];
#pragma unroll
    for (int mr = 0; mr < 8; ++mr) {
      int row = rbase + mr * 16;
#pragma unroll
      for (int r = 0; r < 4; ++r)
        Z[(size_t)(row + r) * LL + col] = acc[mr][nr][r] + be;
    }
  }
}

// ---------------------------------------------------------------------------
// Kernel 4: per-row top-64 classify on |zhat|. 15-round radix descent on the
// TOP 16 BITS of the fp32 bit pattern. sure: |zhat| > bucket_hi + TAU.
// window: |zhat| in [bucket_lo - TAU, bucket_hi + TAU] -> fixup.
// ---------------------------------------------------------------------------
__global__ __launch_bounds__(256) void topk_kernel(
    const float* __restrict__ Z, float* __restrict__ ZS,
    int* __restrict__ TKI, float* __restrict__ TKV,
    int* __restrict__ WIDX, int* __restrict__ META, int r0) {
  int lrow = blockIdx.x, grow = r0 + lrow, t = threadIdx.x;
  const float* zr = Z + (size_t)lrow * LL;
  float* zs = ZS + (size_t)lrow * LL;

  uint4 kv[16];  // |zhat| bit keys, 64 per thread
#pragma unroll
  for (int i = 0; i < 16; ++i) {
    float4 v = ((const float4*)zr)[t + i * 256];
    kv[i].x = __float_as_uint(v.x) & 0x7fffffffu;
    kv[i].y = __float_as_uint(v.y) & 0x7fffffffu;
    kv[i].z = __float_as_uint(v.z) & 0x7fffffffu;
    kv[i].w = __float_as_uint(v.w) & 0x7fffffffu;
  }
  float4 z4 = {0.f, 0.f, 0.f, 0.f};
#pragma unroll
  for (int i = 0; i < 16; ++i) ((float4*)zs)[t + i * 256] = z4;

  __shared__ int red[4];
  unsigned cut = 0;  // prefix over bits 30..16; low 16 bits stay 0
  for (int bit = 30; bit >= 16; --bit) {
    unsigned ct = cut | (1u << bit);
    int cnt = 0;
#pragma unroll
    for (int i = 0; i < 16; ++i)
      cnt += (kv[i].x >= ct) + (kv[i].y >= ct) + (kv[i].z >= ct) + (kv[i].w >= ct);
    for (int off = 32; off > 0; off >>= 1) cnt += __shfl_down(cnt, off, 64);
    if ((t & 63) == 0) red[t >> 6] = cnt;
    __syncthreads();
    int total = red[0] + red[1] + red[2] + red[3];
    if (total >= KT) cut = ct;
    __syncthreads();
  }

  float c16 = __uint_as_float(cut);
  float cnx = __uint_as_float(cut + 0x10000u);
  float chi = cnx + TAU;
  float clo = c16 - TAU; if (clo < 0.f) clo = 0.f;
  unsigned hiKey = __float_as_uint(chi);
  unsigned loKey = (clo > 0.f) ? __float_as_uint(clo) : 0u;

  __shared__ unsigned nsel, ntie;
  if (t == 0) { nsel = 0; ntie = 0; }
  __syncthreads();

#pragma unroll
  for (int i = 0; i < 16; ++i) {
    int base = 4 * (t + i * 256);
    unsigned k4[4] = {kv[i].x, kv[i].y, kv[i].z, kv[i].w};
#pragma unroll
    for (int q = 0; q < 4; ++q) {
      unsigned key = k4[q];
      int idx = base + q;
      if (key > hiKey) {
        unsigned p = atomicAdd(&nsel, 1u);
        if (p < KT) {
          float v = zr[idx];
          TKI[grow * KT + p] = idx;
          TKV[grow * KT + p] = v;
          zs[idx] = v;
        }
      } else if (key >= loKey) {
        unsigned p = atomicAdd(&ntie, 1u);
        if (p < WCAP) WIDX[grow * WCAP + p] = idx;
      }
    }
  }
  __syncthreads();
  int ns = (int)nsel; if (ns > KT) ns = KT;
  if (t >= ns && t < KT) { TKI[grow * KT + t] = 0; TKV[grow * KT + t] = 0.f; }
  if (t == 0) {
    int wc = (int)ntie; if (wc > WCAP) wc = WCAP;
    META[grow * 2 + 0] = ns;
    META[grow * 2 + 1] = wc;
  }
}

// ---------------------------------------------------------------------------
// Kernel 5: fixup — fill the (64 - nsure) remaining slots from the window.
// ---------------------------------------------------------------------------
__global__ __launch_bounds__(256) void fixup_kernel(
    const float* __restrict__ X32, const float* __restrict__ W,
    const float* __restrict__ benc, const u16* __restrict__ Wh,
    const u16* __restrict__ Wl, const float* __restrict__ Z,
    float* __restrict__ ZS, const int* __restrict__ WIDX,
    const int* __restrict__ META, int* __restrict__ TKI,
    float* __restrict__ TKV, int r0) {
  int lrow = blockIdx.x, grow = r0 + lrow, t = threadIdx.x;
  int nsure = META[grow * 2 + 0];
  int wcnt = META[grow * 2 + 1];
  int deferred = KT - nsure;
  if (deferred <= 0) return;              // uniform exit per block
  if (deferred > wcnt) deferred = wcnt;   // safety (tau violation; degrade soft)

  __shared__ int widx[WCAP];
  if (t < wcnt) widx[t] = WIDX[grow * WCAP + t];
  __syncthreads();

  if (wcnt == deferred) {  // uncontested: take all (zhat values)
    if (t < wcnt) {
      int idx = widx[t];
      float v = Z[(size_t)lrow * LL + idx];
      TKI[grow * KT + nsure + t] = idx;
      TKV[grow * KT + nsure + t] = v;
      ZS[(size_t)lrow * LL + idx] = v;
    }
    return;
  }

  // contested: mid-tier recompute for all candidates
  __shared__ float xs[DD];
  __shared__ double wz[WCAP];
  __shared__ double wr[4];
  __shared__ int exact_flag[WCAP];
  for (int i = t; i < DD; i += 256) xs[i] = X32[(size_t)grow * DD + i];
  __syncthreads();
  for (int j = 0; j < wcnt; ++j) {
    int idx = widx[j];
    const u16* wh = Wh + (size_t)idx * DD;
    const u16* wl = Wl + (size_t)idx * DD;
    double p = 0.0;
    for (int k = t; k < DD; k += 256)
      p += (double)xs[k] * ((double)bf2f(wh[k]) + (double)bf2f(wl[k]));
    for (int off = 32; off > 0; off >>= 1) p += __shfl_down(p, off, 64);
    if ((t & 63) == 0) wr[t >> 6] = p;
    __syncthreads();
    if (t == 0) wz[j] = wr[0] + wr[1] + wr[2] + wr[3] + (double)benc[idx];
    __syncthreads();
  }

  // tier-3 marking: boundary = deferred-th largest |wz|; flag near-boundary
  if (t == 0) {
    int taken = 0;
    double b = 0.0;
    for (int s = 0; s < deferred; ++s) {
      int best = -1; double bv = -1.0;
      for (int j = 0; j < wcnt; ++j) {
        if (taken & (1 << j)) continue;
        double a = fabs(wz[j]);
        if (best < 0 || a > bv || (a == bv && widx[j] < widx[best])) { best = j; bv = a; }
      }
      taken |= (1 << best);
      b = bv;
    }
    for (int j = 0; j < wcnt; ++j)
      exact_flag[j] = (fabs(fabs(wz[j]) - b) < (double)T3) ? 1 : 0;
  }
  __syncthreads();
  for (int j = 0; j < wcnt; ++j) {
    if (!exact_flag[j]) continue;  // uniform per block (shared flag)
    int idx = widx[j];
    double p = 0.0;
    for (int k = t; k < DD; k += 256)
      p += (double)xs[k] * (double)W[(size_t)k * LL + idx];
    for (int off = 32; off > 0; off >>= 1) p += __shfl_down(p, off, 64);
    if ((t & 63) == 0) wr[t >> 6] = p;
    __syncthreads();
    if (t == 0) wz[j] = wr[0] + wr[1] + wr[2] + wr[3] + (double)benc[idx];
    __syncthreads();
  }

  if (t == 0) {
    int taken = 0;
    for (int s = 0; s < deferred; ++s) {
      int best = -1; double bv = -1.0;
      for (int j = 0; j < wcnt; ++j) {
        if (taken & (1 << j)) continue;
        double a = fabs(wz[j]);
        if (best < 0 || a > bv || (a == bv && widx[j] < widx[best])) { best = j; bv = a; }
      }
      taken |= (1 << best);
      int idx = widx[best];
      float v = (float)wz[best];
      TKI[grow * KT + nsure + s] = idx;
      TKV[grow * KT + nsure + s] = v;
      ZS[(size_t)lrow * LL + idx] = v;
    }
  }
}

// ---------------------------------------------------------------------------
// Kernel 6: decode  recon[b,d] = b_dec[d] + sum_j val_j * Wh[idx_j, d]
// ---------------------------------------------------------------------------
__global__ __launch_bounds__(256) void decode_kernel(
    const u16* __restrict__ Wh, const float* __restrict__ bdec,
    const int* __restrict__ TKI, const float* __restrict__ TKV,
    float* __restrict__ OUT) {
  int row = blockIdx.x, t = threadIdx.x;
  __shared__ int sidx[KT];
  __shared__ float sval[KT];
  if (t < KT) {
    sidx[t] = TKI[row * KT + t] & (LL - 1);
    sval[t] = TKV[row * KT + t];
  }
  __syncthreads();
  int d0 = t * 8;
  float acc[8] = {0.f, 0.f, 0.f, 0.f, 0.f, 0.f, 0.f, 0.f};
#pragma unroll 4
  for (int j = 0; j < KT; ++j) {
    const u16x8 wv = *(const u16x8*)(Wh + (size_t)sidx[j] * DD + d0);
    float v = sval[j];
#pragma unroll
    for (int e = 0; e < 8; ++e) acc[e] = fmaf(v, bf2f(wv[e]), acc[e]);
  }
  float4 o0, o1;
  o0.x = acc[0] + bdec[d0 + 0]; o0.y = acc[1] + bdec[d0 + 1];
  o0.z = acc[2] + bdec[d0 + 2]; o0.w = acc[3] + bdec[d0 + 3];
  o1.x = acc[4] + bdec[d0 + 4]; o1.y = acc[5] + bdec[d0 + 5];
  o1.z = acc[6] + bdec[d0 + 6]; o1.w = acc[7] + bdec[d0 + 7];
  float* dst = OUT + (size_t)row * DD + d0;
  *(float4*)dst = o0;
  *(float4*)(dst + 4) = o1;
}

// ---------------------------------------------------------------------------
// ws layout (fixed ~153.5 MB + adaptive fp32 Z chunk):
//  [Xh 16M][Wh 64M][Wl 64M][TKI 1M][TKV 1M][WIDX 384K][META 32K][Zc ...]
// ---------------------------------------------------------------------------
extern "C" void kernel_launch(void* const* d_in, const int* in_sizes, int n_in,
                              void* d_out, int out_size, void* d_ws,
                              size_t ws_size, hipStream_t stream) {
  const float* X = (const float*)d_in[0];     // [4096, 2048] fp32
  const float* W = (const float*)d_in[1];     // [2048, 16384] fp32
  const float* benc = (const float*)d_in[2];  // [16384] fp32
  const float* bdec = (const float*)d_in[3];  // [2048] fp32

  char* ws = (char*)d_ws;
  const size_t XH_B = (size_t)NB * DD * 2;      // 16,777,216
  const size_t WH_B = (size_t)LL * DD * 2;      // 67,108,864
  const size_t TKI_B = (size_t)NB * KT * 4;     // 1,048,576
  const size_t WIDX_B = (size_t)NB * WCAP * 4;  // 393,216
  const size_t META_B = (size_t)NB * 2 * 4;     // 32,768
  u16* Xh = (u16*)ws;
  u16* Wh = (u16*)(ws + XH_B);
  u16* Wl = (u16*)(ws + XH_B + WH_B);
  int* TKI = (int*)(ws + XH_B + 2 * WH_B);
  float* TKV = (float*)(ws + XH_B + 2 * WH_B + TKI_B);
  int* WIDX = (int*)(ws + XH_B + 2 * WH_B + 2 * TKI_B);
  int* META = (int*)(ws + XH_B + 2 * WH_B + 2 * TKI_B + WIDX_B);
  float* Zc = (float*)(ws + XH_B + 2 * WH_B + 2 * TKI_B + WIDX_B + META_B);

  size_t fixed = XH_B + 2 * WH_B + 2 * TKI_B + WIDX_B + META_B;
  size_t avail = (ws_size > fixed) ? (ws_size - fixed) : 0;
  int chunk = (int)(avail / ((size_t)LL * 4));
  chunk = (chunk / TBM) * TBM;
  if (chunk > NB) chunk = NB;
  if (chunk < TBM) chunk = TBM;

  float* out_recon = (float*)d_out;                    // [4096, 2048]
  float* out_zs = (float*)d_out + (size_t)NB * DD;     // [4096, 16384]

  prep_x<<<NB * DD / 1024, 256, 0, stream>>>(X, Xh);
  prep_w<<<dim3(LL / 64, DD / 64), 256, 0, stream>>>(W, Wh, Wl);
  for (int r0 = 0; r0 < NB; r0 += chunk) {
    int rows = NB - r0; if (rows > chunk) rows = chunk;
    encode_gemm<<<dim3(LL / TBN, rows / TBM), 512, 0, stream>>>(
        Xh + (size_t)r0 * DD, Wh, benc, Zc);
    topk_kernel<<<rows, 256, 0, stream>>>(
        Zc, out_zs + (size_t)r0 * LL, TKI, TKV, WIDX, META, r0);
    fixup_kernel<<<rows, 256, 0, stream>>>(
        X, W, benc, Wh, Wl, Zc, out_zs + (size_t)r0 * LL, WIDX, META, TKI,
        TKV, r0);
  }
  decode_kernel<<<NB, 256, 0, stream>>>(Wh, bdec, TKI, TKV, out_recon);
}

// Round 2
// 1182.261 us; speedup vs baseline: 1.0993x; 1.0395x over previous
//
#include <hip/hip_runtime.h>
#include <stdint.h>

// Problem constants (B, D, L, K from the reference). fp32 I/O per reference.
#define NB 4096
#define DD 2048
#define LL 16384
#define KT 64
#define WCAP 24        // window candidate cap per row
#define TAU 1.2e-2f    // sure/window margin: 5.7 sigma of zhat error (hh-only)
#define T3 1e-4f       // tier-3 exact-fp64 gap threshold (matches round-3 exposure)

typedef unsigned short u16;
typedef __bf16 bf16x8 __attribute__((ext_vector_type(8)));
typedef float f32x4 __attribute__((ext_vector_type(4)));
typedef unsigned short u16x4 __attribute__((ext_vector_type(4)));
typedef unsigned short u16x8 __attribute__((ext_vector_type(8)));

__device__ __forceinline__ float bf2f(u16 b) {
  return __uint_as_float(((unsigned)b) << 16);
}
__device__ __forceinline__ u16 f2bf(float f) {
  unsigned u = __float_as_uint(f);
  unsigned r = u + 0x7fffu + ((u >> 16) & 1u);  // RNE
  return (u16)(r >> 16);
}

// ---------------------------------------------------------------------------
// Kernel 1: X fp32 -> Xh bf16 (hi part only; fixup reads fp32 X directly)
// ---------------------------------------------------------------------------
__global__ __launch_bounds__(256) void prep_x(const float* __restrict__ X,
                                              u16* __restrict__ Xh) {
  int i = (blockIdx.x * 256 + threadIdx.x) * 4;
  float4 v = *(const float4*)(X + i);
  u16x4 h;
  h[0] = f2bf(v.x); h[1] = f2bf(v.y); h[2] = f2bf(v.z); h[3] = f2bf(v.w);
  *(u16x4*)(Xh + i) = h;
}

// ---------------------------------------------------------------------------
// Kernel 2: transpose + split W fp32 [2048,16384] -> Wh/Wl bf16 [16384,2048]
// ---------------------------------------------------------------------------
__global__ __launch_bounds__(256) void prep_w(const float* __restrict__ W,
                                              u16* __restrict__ Wh,
                                              u16* __restrict__ Wl) {
  __shared__ float tile[64][65];  // +1 pad breaks write-phase bank aliasing
  int l0 = blockIdx.x * 64, d0 = blockIdx.y * 64;
  int t = threadIdx.x;
  int lx = (t & 15) * 4;
  int dq = t >> 4;
#pragma unroll
  for (int p = 0; p < 4; ++p) {
    int d = dq + p * 16;
    float4 v = *(const float4*)(W + (size_t)(d0 + d) * LL + l0 + lx);
    tile[d][lx + 0] = v.x; tile[d][lx + 1] = v.y;
    tile[d][lx + 2] = v.z; tile[d][lx + 3] = v.w;
  }
  __syncthreads();
  int dx = (t & 15) * 4;
  int lq = t >> 4;
#pragma unroll
  for (int p = 0; p < 4; ++p) {
    int l = lq + p * 16;
    u16x4 h, lo;
#pragma unroll
    for (int q = 0; q < 4; ++q) {
      float w = tile[dx + q][l];
      u16 hb = f2bf(w);
      h[q] = hb;
      lo[q] = f2bf(w - bf2f(hb));
    }
    size_t o = (size_t)(l0 + l) * DD + d0 + dx;
    *(u16x4*)(Wh + o) = h;
    *(u16x4*)(Wl + o) = lo;
  }
}

// ---------------------------------------------------------------------------
// Kernel 3: encode GEMM  zhat = Xh·Wh^T + benc
// 256x256 tile, BK=64, 8 waves (2Mx4N, 128x64 out/wave).
// Read-ahead pipeline (lgkm analog of T4's counted vmcnt): all A reads + bq
// NQ0 issue in Pa; Q00 starts at lgkmcnt(8) while af1's 8 reads stay in
// flight through Pa's MFMA; bq NQ1 reloads AFTER Pb's MFMA (hidden under the
// barrier + Pc window). Per tile: Pa{20 reads}, Pb{4 post-MFMA}, Pc/Pd{0} —
// LDS drain overlaps the MFMA windows instead of serializing per phase.
// Staging placements/gates identical to prev round (WAR re-derived: each
// STAGE into a region issues only after the barrier following the region's
// last readers' lgkm-wait). vmcnt(6) counted gate once per tile, never 0 in
// the main loop. XOR bank-swizzle on both global_load_lds source and ds_read
// (rule #21). Numerics identical (same MFMA, same K order).
// ---------------------------------------------------------------------------
#define TBM 256
#define TBN 256
#define TBK 64
#define NKT (DD / TBK)  // 32 K-tiles, 16 iterations of 2

__device__ __forceinline__ void async16(const u16* g, u16* l) {
  __builtin_amdgcn_global_load_lds(
      (const __attribute__((address_space(1))) unsigned int*)g,
      (__attribute__((address_space(3))) unsigned int*)l, 16, 0, 0);
}

// HF: 0=A.h0 1=A.h1 2=B.h0 3=B.h1 (compile-time); TAU_ = K-tile index.
#define STAGE(HF, TAU_)                                                      \
  do {                                                                       \
    const u16* g_ = ((HF) < 2 ? Abase : Bbase) +                             \
                    (size_t)(((HF)&1) * 128 + rr) * DD + ((TAU_) << 6) +     \
                    scol;                                                    \
    u16* l_ = ((HF) < 2 ? As : Bs) + ((TAU_)&1) * (TBM * TBK) +              \
              (((HF)&1) * 128) * TBK + t * 8;                                \
    async16(g_, l_);                                                         \
    async16(g_ + (size_t)64 * DD, l_ + 4096);                                \
  } while (0)

// Load one A m-quadrant (4 mreps x 2 ksubs = 8 x ds_read_b128) into DST.
#define LDA(DST, DB, MQ)                                                     \
  do {                                                                       \
    const u16* p_ = As + (DB) * (TBM * TBK) + (wm + (MQ)*64 + fr) * TBK;     \
    _Pragma("unroll") for (int i_ = 0; i_ < 4; ++i_) {                       \
      DST[i_][0] = *(const bf16x8*)(p_ + i_ * (16 * TBK) + c0);              \
      DST[i_][1] = *(const bf16x8*)(p_ + i_ * (16 * TBK) + c1);              \
    }                                                                        \
  } while (0)

// Load one B n-quadrant (2 nreps x 2 ksubs = 4 x ds_read_b128) into bq.
#define LDBQ(DB, NQ)                                                         \
  do {                                                                       \
    const u16* p_ = Bs + (DB) * (TBN * TBK) + (wn + (NQ)*32 + fr) * TBK;     \
    _Pragma("unroll") for (int j_ = 0; j_ < 2; ++j_) {                       \
      bq[j_][0] = *(const bf16x8*)(p_ + j_ * (16 * TBK) + c0);               \
      bq[j_][1] = *(const bf16x8*)(p_ + j_ * (16 * TBK) + c1);               \
    }                                                                        \
  } while (0)

// One C-quadrant x K=64: 4x2 frags x 2 chained ksubs = 16 MFMA.
#define MFMAQ(AF, MQ, NQ)                                                    \
  do {                                                                       \
    _Pragma("unroll") for (int i_ = 0; i_ < 4; ++i_)                         \
        _Pragma("unroll") for (int j_ = 0; j_ < 2; ++j_) {                   \
      f32x4 a_ = acc[(MQ)*4 + i_][(NQ)*2 + j_];                              \
      a_ = __builtin_amdgcn_mfma_f32_16x16x32_bf16(AF[i_][0], bq[j_][0], a_, \
                                                   0, 0, 0);                 \
      a_ = __builtin_amdgcn_mfma_f32_16x16x32_bf16(AF[i_][1], bq[j_][1], a_, \
                                                   0, 0, 0);                 \
      acc[(MQ)*4 + i_][(NQ)*2 + j_] = a_;                                    \
    }                                                                        \
  } while (0)

#define BAR __builtin_amdgcn_s_barrier()
#define LGKM0 asm volatile("s_waitcnt lgkmcnt(0)")
#define LGKM8 asm volatile("s_waitcnt lgkmcnt(8)")
#define PRIO1 __builtin_amdgcn_s_setprio(1)
#define PRIO0 __builtin_amdgcn_s_setprio(0)

__global__ __launch_bounds__(512, 2) void encode_gemm(
    const u16* __restrict__ Xh,   // [rows,2048] (pre-offset to chunk)
    const u16* __restrict__ Wh,   // [16384,2048]
    const float* __restrict__ benc,
    float* __restrict__ Z) {      // [rows,16384]
  __shared__ u16 As[2 * TBM * TBK];  // 64 KB (2 dbuf x 256 x 64)
  __shared__ u16 Bs[2 * TBN * TBK];  // 64 KB
  int t = threadIdx.x;
  int m0 = blockIdx.y * TBM;
  int n0 = blockIdx.x * TBN;

  int lane = t & 63, w = t >> 6;
  int wm = (w & 1) * 128;   // wave M offset (2 waves in M)
  int wn = (w >> 1) * 64;   // wave N offset (4 waves in N)
  int fr = lane & 15;
  int fq = lane >> 4;
  // swizzled ds_read column granules (elements), ksub 0 / ksub 1
  int c0 = ((fq ^ (fr & 7)) << 3);
  int c1 = (((4 + fq) ^ (fr & 7)) << 3);
  // staging: thread t covers row rr (per q: +0/+64), slot t&7, swizzled src
  int rr = t >> 3;
  int scol = (((t & 7) ^ (rr & 7)) << 3);

  const u16* Abase = Xh + (size_t)m0 * DD;
  const u16* Bbase = Wh + (size_t)n0 * DD;

  f32x4 acc[8][4] = {};
  bf16x8 af0[4][2], af1[4][2], bq[2][2];

  // ---- prologue: stage tile0 (4 halves) + tile1 {Ah0,Ah1,Bh0} ----
  STAGE(0, 0); STAGE(1, 0); STAGE(2, 0); STAGE(3, 0);
  asm volatile("s_waitcnt vmcnt(4)" ::: "memory");
  STAGE(0, 1); STAGE(1, 1); STAGE(2, 1);
  asm volatile("s_waitcnt vmcnt(6)" ::: "memory");  // tile0 fully landed
  BAR;

  for (int it = 0; it < NKT / 2; ++it) {
    const int notlast = (it < NKT / 2 - 1);
    // ================= tile 2it (buf0) =================
    // Pa: ALL A reads + bq<-NQ0 (20 ds_reads); stage [2it+1].Bh1.
    // lgkm(8): af0+bq ready, af1's 8 still in flight under Q00's MFMA.
    LDA(af0, 0, 0);
    LDBQ(0, 0);
    LDA(af1, 0, 1);
    STAGE(3, 2 * it + 1);
    BAR; LGKM8; PRIO1; MFMAQ(af0, 0, 0); PRIO0; BAR;
    // Pb: af1 now ready; Q10; then reload bq<-NQ1 AFTER the MFMA (its
    // latency hides under the closing barrier + Pc's window).
    LGKM0; PRIO1; MFMAQ(af1, 1, 0); PRIO0;
    LDBQ(0, 1);
    BAR;
    // Pc: stage [2it+2].Ah0 (A reads all completed cross-wave at Pb's BAR)
    if (notlast) STAGE(0, 2 * it + 2);
    BAR; LGKM0; PRIO1; MFMAQ(af0, 0, 1); PRIO0; BAR;
    // Pd: stage [2it+2].{Ah1,Bh0}; pure-register Q11; counted vmcnt gate
    if (notlast) { STAGE(1, 2 * it + 2); STAGE(2, 2 * it + 2); }
    BAR; PRIO1; MFMAQ(af1, 1, 1); PRIO0;
    if (notlast) asm volatile("s_waitcnt vmcnt(6)" ::: "memory");
    else         asm volatile("s_waitcnt vmcnt(0)" ::: "memory");
    BAR;  // tile 2it+1 fully landed in buf1
    // ================= tile 2it+1 (buf1) =================
    // Pe
    LDA(af0, 1, 0);
    LDBQ(1, 0);
    LDA(af1, 1, 1);
    if (notlast) STAGE(3, 2 * it + 2);
    BAR; LGKM8; PRIO1; MFMAQ(af0, 0, 0); PRIO0; BAR;
    // Pf
    LGKM0; PRIO1; MFMAQ(af1, 1, 0); PRIO0;
    LDBQ(1, 1);
    BAR;
    // Pg
    if (notlast) STAGE(0, 2 * it + 3);
    BAR; LGKM0; PRIO1; MFMAQ(af0, 0, 1); PRIO0; BAR;
    // Ph
    if (notlast) { STAGE(1, 2 * it + 3); STAGE(2, 2 * it + 3); }
    BAR; PRIO1; MFMAQ(af1, 1, 1); PRIO0;
    if (notlast) asm volatile("s_waitcnt vmcnt(6)" ::: "memory");
    BAR;  // tile 2it+2 fully landed in buf0
  }

  // ---- epilogue: C/D layout col = lane&15, row = (lane>>4)*4 + reg ----
  int rbase = m0 + wm + fq * 4;
#pragma unroll
  for (int nr = 0; nr < 4; ++nr) {
    int col = n0 + wn + nr * 16 + fr;
    float be = benc[col];
#pragma unroll
    for (int mr = 0; mr < 8; ++mr) {
      int row = rbase + mr * 16;
#pragma unroll
      for (int r = 0; r < 4; ++r)
        Z[(size_t)(row + r) * LL + col] = acc[mr][nr][r] + be;
    }
  }
}

// ---------------------------------------------------------------------------
// Kernel 4: per-row top-64 classify on |zhat|. 15-round radix descent on the
// TOP 16 BITS of the fp32 bit pattern. sure: |zhat| > bucket_hi + TAU.
// window: |zhat| in [bucket_lo - TAU, bucket_hi + TAU] -> fixup.
// ---------------------------------------------------------------------------
__global__ __launch_bounds__(256) void topk_kernel(
    const float* __restrict__ Z, float* __restrict__ ZS,
    int* __restrict__ TKI, float* __restrict__ TKV,
    int* __restrict__ WIDX, int* __restrict__ META, int r0) {
  int lrow = blockIdx.x, grow = r0 + lrow, t = threadIdx.x;
  const float* zr = Z + (size_t)lrow * LL;
  float* zs = ZS + (size_t)lrow * LL;

  uint4 kv[16];  // |zhat| bit keys, 64 per thread
#pragma unroll
  for (int i = 0; i < 16; ++i) {
    float4 v = ((const float4*)zr)[t + i * 256];
    kv[i].x = __float_as_uint(v.x) & 0x7fffffffu;
    kv[i].y = __float_as_uint(v.y) & 0x7fffffffu;
    kv[i].z = __float_as_uint(v.z) & 0x7fffffffu;
    kv[i].w = __float_as_uint(v.w) & 0x7fffffffu;
  }
  float4 z4 = {0.f, 0.f, 0.f, 0.f};
#pragma unroll
  for (int i = 0; i < 16; ++i) ((float4*)zs)[t + i * 256] = z4;

  __shared__ int red[4];
  unsigned cut = 0;  // prefix over bits 30..16; low 16 bits stay 0
  for (int bit = 30; bit >= 16; --bit) {
    unsigned ct = cut | (1u << bit);
    int cnt = 0;
#pragma unroll
    for (int i = 0; i < 16; ++i)
      cnt += (kv[i].x >= ct) + (kv[i].y >= ct) + (kv[i].z >= ct) + (kv[i].w >= ct);
    for (int off = 32; off > 0; off >>= 1) cnt += __shfl_down(cnt, off, 64);
    if ((t & 63) == 0) red[t >> 6] = cnt;
    __syncthreads();
    int total = red[0] + red[1] + red[2] + red[3];
    if (total >= KT) cut = ct;
    __syncthreads();
  }

  float c16 = __uint_as_float(cut);
  float cnx = __uint_as_float(cut + 0x10000u);
  float chi = cnx + TAU;
  float clo = c16 - TAU; if (clo < 0.f) clo = 0.f;
  unsigned hiKey = __float_as_uint(chi);
  unsigned loKey = (clo > 0.f) ? __float_as_uint(clo) : 0u;

  __shared__ unsigned nsel, ntie;
  if (t == 0) { nsel = 0; ntie = 0; }
  __syncthreads();

#pragma unroll
  for (int i = 0; i < 16; ++i) {
    int base = 4 * (t + i * 256);
    unsigned k4[4] = {kv[i].x, kv[i].y, kv[i].z, kv[i].w};
#pragma unroll
    for (int q = 0; q < 4; ++q) {
      unsigned key = k4[q];
      int idx = base + q;
      if (key > hiKey) {
        unsigned p = atomicAdd(&nsel, 1u);
        if (p < KT) {
          float v = zr[idx];
          TKI[grow * KT + p] = idx;
          TKV[grow * KT + p] = v;
          zs[idx] = v;
        }
      } else if (key >= loKey) {
        unsigned p = atomicAdd(&ntie, 1u);
        if (p < WCAP) WIDX[grow * WCAP + p] = idx;
      }
    }
  }
  __syncthreads();
  int ns = (int)nsel; if (ns > KT) ns = KT;
  if (t >= ns && t < KT) { TKI[grow * KT + t] = 0; TKV[grow * KT + t] = 0.f; }
  if (t == 0) {
    int wc = (int)ntie; if (wc > WCAP) wc = WCAP;
    META[grow * 2 + 0] = ns;
    META[grow * 2 + 1] = wc;
  }
}

// ---------------------------------------------------------------------------
// Kernel 5: fixup — fill the (64 - nsure) remaining slots from the window.
// ---------------------------------------------------------------------------
__global__ __launch_bounds__(256) void fixup_kernel(
    const float* __restrict__ X32, const float* __restrict__ W,
    const float* __restrict__ benc, const u16* __restrict__ Wh,
    const u16* __restrict__ Wl, const float* __restrict__ Z,
    float* __restrict__ ZS, const int* __restrict__ WIDX,
    const int* __restrict__ META, int* __restrict__ TKI,
    float* __restrict__ TKV, int r0) {
  int lrow = blockIdx.x, grow = r0 + lrow, t = threadIdx.x;
  int nsure = META[grow * 2 + 0];
  int wcnt = META[grow * 2 + 1];
  int deferred = KT - nsure;
  if (deferred <= 0) return;              // uniform exit per block
  if (deferred > wcnt) deferred = wcnt;   // safety (tau violation; degrade soft)

  __shared__ int widx[WCAP];
  if (t < wcnt) widx[t] = WIDX[grow * WCAP + t];
  __syncthreads();

  if (wcnt == deferred) {  // uncontested: take all (zhat values)
    if (t < wcnt) {
      int idx = widx[t];
      float v = Z[(size_t)lrow * LL + idx];
      TKI[grow * KT + nsure + t] = idx;
      TKV[grow * KT + nsure + t] = v;
      ZS[(size_t)lrow * LL + idx] = v;
    }
    return;
  }

  // contested: mid-tier recompute for all candidates
  __shared__ float xs[DD];
  __shared__ double wz[WCAP];
  __shared__ double wr[4];
  __shared__ int exact_flag[WCAP];
  for (int i = t; i < DD; i += 256) xs[i] = X32[(size_t)grow * DD + i];
  __syncthreads();
  for (int j = 0; j < wcnt; ++j) {
    int idx = widx[j];
    const u16* wh = Wh + (size_t)idx * DD;
    const u16* wl = Wl + (size_t)idx * DD;
    double p = 0.0;
    for (int k = t; k < DD; k += 256)
      p += (double)xs[k] * ((double)bf2f(wh[k]) + (double)bf2f(wl[k]));
    for (int off = 32; off > 0; off >>= 1) p += __shfl_down(p, off, 64);
    if ((t & 63) == 0) wr[t >> 6] = p;
    __syncthreads();
    if (t == 0) wz[j] = wr[0] + wr[1] + wr[2] + wr[3] + (double)benc[idx];
    __syncthreads();
  }

  // tier-3 marking: boundary = deferred-th largest |wz|; flag near-boundary
  if (t == 0) {
    int taken = 0;
    double b = 0.0;
    for (int s = 0; s < deferred; ++s) {
      int best = -1; double bv = -1.0;
      for (int j = 0; j < wcnt; ++j) {
        if (taken & (1 << j)) continue;
        double a = fabs(wz[j]);
        if (best < 0 || a > bv || (a == bv && widx[j] < widx[best])) { best = j; bv = a; }
      }
      taken |= (1 << best);
      b = bv;
    }
    for (int j = 0; j < wcnt; ++j)
      exact_flag[j] = (fabs(fabs(wz[j]) - b) < (double)T3) ? 1 : 0;
  }
  __syncthreads();
  for (int j = 0; j < wcnt; ++j) {
    if (!exact_flag[j]) continue;  // uniform per block (shared flag)
    int idx = widx[j];
    double p = 0.0;
    for (int k = t; k < DD; k += 256)
      p += (double)xs[k] * (double)W[(size_t)k * LL + idx];
    for (int off = 32; off > 0; off >>= 1) p += __shfl_down(p, off, 64);
    if ((t & 63) == 0) wr[t >> 6] = p;
    __syncthreads();
    if (t == 0) wz[j] = wr[0] + wr[1] + wr[2] + wr[3] + (double)benc[idx];
    __syncthreads();
  }

  if (t == 0) {
    int taken = 0;
    for (int s = 0; s < deferred; ++s) {
      int best = -1; double bv = -1.0;
      for (int j = 0; j < wcnt; ++j) {
        if (taken & (1 << j)) continue;
        double a = fabs(wz[j]);
        if (best < 0 || a > bv || (a == bv && widx[j] < widx[best])) { best = j; bv = a; }
      }
      taken |= (1 << best);
      int idx = widx[best];
      float v = (float)wz[best];
      TKI[grow * KT + nsure + s] = idx;
      TKV[grow * KT + nsure + s] = v;
      ZS[(size_t)lrow * LL + idx] = v;
    }
  }
}

// ---------------------------------------------------------------------------
// Kernel 6: decode  recon[b,d] = b_dec[d] + sum_j val_j * Wh[idx_j, d]
// unroll 8: deeper outstanding-load pipeline for the L3-latency-bound gather
// ---------------------------------------------------------------------------
__global__ __launch_bounds__(256) void decode_kernel(
    const u16* __restrict__ Wh, const float* __restrict__ bdec,
    const int* __restrict__ TKI, const float* __restrict__ TKV,
    float* __restrict__ OUT) {
  int row = blockIdx.x, t = threadIdx.x;
  __shared__ int sidx[KT];
  __shared__ float sval[KT];
  if (t < KT) {
    sidx[t] = TKI[row * KT + t] & (LL - 1);
    sval[t] = TKV[row * KT + t];
  }
  __syncthreads();
  int d0 = t * 8;
  float acc[8] = {0.f, 0.f, 0.f, 0.f, 0.f, 0.f, 0.f, 0.f};
#pragma unroll 8
  for (int j = 0; j < KT; ++j) {
    const u16x8 wv = *(const u16x8*)(Wh + (size_t)sidx[j] * DD + d0);
    float v = sval[j];
#pragma unroll
    for (int e = 0; e < 8; ++e) acc[e] = fmaf(v, bf2f(wv[e]), acc[e]);
  }
  float4 o0, o1;
  o0.x = acc[0] + bdec[d0 + 0]; o0.y = acc[1] + bdec[d0 + 1];
  o0.z = acc[2] + bdec[d0 + 2]; o0.w = acc[3] + bdec[d0 + 3];
  o1.x = acc[4] + bdec[d0 + 4]; o1.y = acc[5] + bdec[d0 + 5];
  o1.z = acc[6] + bdec[d0 + 6]; o1.w = acc[7] + bdec[d0 + 7];
  float* dst = OUT + (size_t)row * DD + d0;
  *(float4*)dst = o0;
  *(float4*)(dst + 4) = o1;
}

// ---------------------------------------------------------------------------
// ws layout (fixed ~153.5 MB + adaptive fp32 Z chunk):
//  [Xh 16M][Wh 64M][Wl 64M][TKI 1M][TKV 1M][WIDX 384K][META 32K][Zc ...]
// ---------------------------------------------------------------------------
extern "C" void kernel_launch(void* const* d_in, const int* in_sizes, int n_in,
                              void* d_out, int out_size, void* d_ws,
                              size_t ws_size, hipStream_t stream) {
  const float* X = (const float*)d_in[0];     // [4096, 2048] fp32
  const float* W = (const float*)d_in[1];     // [2048, 16384] fp32
  const float* benc = (const float*)d_in[2];  // [16384] fp32
  const float* bdec = (const float*)d_in[3];  // [2048] fp32

  char* ws = (char*)d_ws;
  const size_t XH_B = (size_t)NB * DD * 2;      // 16,777,216
  const size_t WH_B = (size_t)LL * DD * 2;      // 67,108,864
  const size_t TKI_B = (size_t)NB * KT * 4;     // 1,048,576
  const size_t WIDX_B = (size_t)NB * WCAP * 4;  // 393,216
  const size_t META_B = (size_t)NB * 2 * 4;     // 32,768
  u16* Xh = (u16*)ws;
  u16* Wh = (u16*)(ws + XH_B);
  u16* Wl = (u16*)(ws + XH_B + WH_B);
  int* TKI = (int*)(ws + XH_B + 2 * WH_B);
  float* TKV = (float*)(ws + XH_B + 2 * WH_B + TKI_B);
  int* WIDX = (int*)(ws + XH_B + 2 * WH_B + 2 * TKI_B);
  int* META = (int*)(ws + XH_B + 2 * WH_B + 2 * TKI_B + WIDX_B);
  float* Zc = (float*)(ws + XH_B + 2 * WH_B + 2 * TKI_B + WIDX_B + META_B);

  size_t fixed = XH_B + 2 * WH_B + 2 * TKI_B + WIDX_B + META_B;
  size_t avail = (ws_size > fixed) ? (ws_size - fixed) : 0;
  int chunk = (int)(avail / ((size_t)LL * 4));
  chunk = (chunk / TBM) * TBM;
  if (chunk > NB) chunk = NB;
  if (chunk < TBM) chunk = TBM;

  float* out_recon = (float*)d_out;                    // [4096, 2048]
  float* out_zs = (float*)d_out + (size_t)NB * DD;     // [4096, 16384]

  prep_x<<<NB * DD / 1024, 256, 0, stream>>>(X, Xh);
  prep_w<<<dim3(LL / 64, DD / 64), 256, 0, stream>>>(W, Wh, Wl);
  for (int r0 = 0; r0 < NB; r0 += chunk) {
    int rows = NB - r0; if (rows > chunk) rows = chunk;
    encode_gemm<<<dim3(LL / TBN, rows / TBM), 512, 0, stream>>>(
        Xh + (size_t)r0 * DD, Wh, benc, Zc);
    topk_kernel<<<rows, 256, 0, stream>>>(
        Zc, out_zs + (size_t)r0 * LL, TKI, TKV, WIDX, META, r0);
    fixup_kernel<<<rows, 256, 0, stream>>>(
        X, W, benc, Wh, Wl, Zc, out_zs + (size_t)r0 * LL, WIDX, META, TKI,
        TKV, r0);
  }
  decode_kernel<<<NB, 256, 0, stream>>>(Wh, bdec, TKI, TKV, out_recon);
}